// Round 1
// 1101.548 us; speedup vs baseline: 1.0128x; 1.0128x over previous
//
#include <hip/hip_runtime.h>
#include <stdint.h>

// ---------------- constants ----------------
#define NN    2048          // nodes
#define BB    16            // batch
#define CC    64            // in channels
#define TT    12            // time
#define OO    64            // out channels
#define ED    10            // embed dim
#define JJ    12288         // B*T*C  (j = (b*T+t)*C + c)
#define NJ    25165824      // NN*JJ
#define KC    192           // 3*C contraction of per-node GEMM
#define NTK   32            // K-tiles in the big GEMM (2048 / 64)

typedef __attribute__((ext_vector_type(8))) short short8;   // 8 bf16 = 4 VGPR
typedef __attribute__((ext_vector_type(4))) float f32x4;

__device__ __forceinline__ unsigned short f2bf(float x) {
    union { float f; unsigned int u; } v; v.f = x;
    unsigned int r = (v.u + 0x7FFFu + ((v.u >> 16) & 1u)) >> 16;
    return (unsigned short)r;
}
__device__ __forceinline__ float bf2f(unsigned short h) {
    union { unsigned int u; float f; } v; v.u = ((unsigned int)h) << 16;
    return v.f;
}
__device__ __forceinline__ void async_cp16(const void* g, void* l) {
    __builtin_amdgcn_global_load_lds(
        (const __attribute__((address_space(1))) void*)(uintptr_t)g,
        (__attribute__((address_space(3))) void*)(uintptr_t)l, 16, 0, 0);
}

// raw barrier: NO vmcnt drain (this is the whole point vs __syncthreads)
__device__ __forceinline__ void phase_barrier() {
    asm volatile("" ::: "memory");
    __builtin_amdgcn_s_barrier();
    __builtin_amdgcn_sched_barrier(0);
}

// ---------------- K1: A = softmax(relu(E E^T)) row-wise -> bf16 ----------------
__global__ __launch_bounds__(256) void k_softmax_A(const float* __restrict__ E,
                                                   unsigned short* __restrict__ Abf) {
    int n = blockIdx.x, tid = threadIdx.x;
    __shared__ float row[NN];
    __shared__ float red[256];
    float en[ED];
#pragma unroll
    for (int d = 0; d < ED; ++d) en[d] = E[n * ED + d];
    float mx = 0.0f;  // relu => values >= 0
    for (int m = tid; m < NN; m += 256) {
        float s = 0.f;
#pragma unroll
        for (int d = 0; d < ED; ++d) s += en[d] * E[m * ED + d];
        s = fmaxf(s, 0.0f);
        row[m] = s;
        mx = fmaxf(mx, s);
    }
    red[tid] = mx; __syncthreads();
    for (int s = 128; s; s >>= 1) { if (tid < s) red[tid] = fmaxf(red[tid], red[tid + s]); __syncthreads(); }
    mx = red[0]; __syncthreads();
    float sum = 0.f;
    for (int m = tid; m < NN; m += 256) { float e = __expf(row[m] - mx); row[m] = e; sum += e; }
    red[tid] = sum; __syncthreads();
    for (int s = 128; s; s >>= 1) { if (tid < s) red[tid] += red[tid + s]; __syncthreads(); }
    float inv = 1.0f / red[0];
    for (int m = tid; m < NN; m += 256) Abf[(size_t)n * NN + m] = f2bf(row[m] * inv);
}

// ---------------- K2: At[w][v] = support[v][w] -> bf16 ----------------
__global__ void k_trans_bf(const float* __restrict__ src, unsigned short* __restrict__ dst) {
    __shared__ float t[32][33];
    int tx = threadIdx.x, ty = threadIdx.y;     // (32, 8)
    int x0 = blockIdx.x * 32, y0 = blockIdx.y * 32;
#pragma unroll
    for (int i = 0; i < 4; ++i)
        t[ty + i * 8][tx] = src[(size_t)(y0 + ty + i * 8) * NN + x0 + tx];
    __syncthreads();
#pragma unroll
    for (int i = 0; i < 4; ++i)
        dst[(size_t)(x0 + ty + i * 8) * NN + y0 + tx] = f2bf(t[tx][ty + i * 8]);
}

// ---------------- K3: X2[n][(b*T+t)*C+c] = x[b][c][n][t] -> bf16 ----------------
__global__ __launch_bounds__(256) void k_make_X2(const float* __restrict__ x,
                                                 unsigned short* __restrict__ X2) {
    int idx = blockIdx.x * 256 + threadIdx.x;   // < NJ
    int n = idx / JJ;
    int r = idx - n * JJ;
    int bt = r >> 6;
    int c = r & 63;
    int b = bt / TT;
    int t = bt - b * TT;
    X2[idx] = f2bf(x[(((size_t)b * CC + c) * NN + n) * TT + t]);
}

// ---------------- K3b: bf16 tiled transpose  dst[j][n] = src[n][j] ----------------
__global__ __launch_bounds__(256) void k_trans16(const unsigned short* __restrict__ src,
                                                 unsigned short* __restrict__ dst) {
    __shared__ unsigned short t[64][72];     // pad 72 shorts
    int tid = threadIdx.x;
    int j0 = blockIdx.x * 64, n0 = blockIdx.y * 64;
    int r = tid >> 3, c8 = (tid & 7) * 8;    // 32 rows per pass, 8 shorts per thread
#pragma unroll
    for (int it = 0; it < 2; ++it) {
        int rr = r + it * 32;
        *(short8*)&t[rr][c8] = *(const short8*)&src[(size_t)(n0 + rr) * JJ + j0 + c8];
    }
    __syncthreads();
#pragma unroll
    for (int it = 0; it < 2; ++it) {
        int rr = r + it * 32;                // j-row within tile
        unsigned short v[8];
#pragma unroll
        for (int u = 0; u < 8; ++u) v[u] = t[c8 + u][rr];
        *(short8*)&dst[(size_t)(j0 + rr) * NN + n0 + c8] = *(short8*)v;
    }
}

// ---------------- K4: 256x256 8-phase bf16 MFMA GEMM ----------------
// Out[m][j] = alpha * sum_k Am[m][k] * Bt[j][k]  (- Csub[m][j])
// Am: [2048][2048] row-major (k contig). Bt: [12288][2048] row-major (k contig).
// grid (48, 8), block 512 (8 waves, wave tile 128x64), dynamic LDS 128 KiB.
// Schedule: per K-tile (BK=64) 4 phases x 16 MFMA; raw s_barrier (no vmcnt drain);
// counted s_waitcnt vmcnt(4) once per K-tile; LDS XOR-swizzle col^=(row&7)<<4
// applied as inverse-swizzled GLOBAL source (global_load_lds dest is linear) +
// swizzled ds_read.  Staging stream: tile t+1's A halves issue in phases 0/1
// (other buffer), tile t+2's B halves in phases 2/3 (current buffer; all B reads
// of the current tile complete by end of phase 1, barrier-ordered).
template <int AOFF, int BOFF>
__device__ __forceinline__ void mfma_quad(f32x4 (&acc)[8][4],
                                          const short8 (&A)[4][2],
                                          const short8 (&B)[2][2]) {
    __builtin_amdgcn_s_setprio(1);
#pragma unroll
    for (int tm = 0; tm < 4; ++tm)
#pragma unroll
        for (int tn = 0; tn < 2; ++tn)
#pragma unroll
            for (int h = 0; h < 2; ++h)
                acc[AOFF + tm][BOFF + tn] = __builtin_amdgcn_mfma_f32_16x16x32_bf16(
                    A[tm][h], B[tn][h], acc[AOFF + tm][BOFF + tn], 0, 0, 0);
    __builtin_amdgcn_s_setprio(0);
}

__global__ __launch_bounds__(512, 2) void k_gemm8(const unsigned short* __restrict__ Am,
                                                  const unsigned short* __restrict__ Bt,
                                                  unsigned short* __restrict__ Out,
                                                  const unsigned short* __restrict__ Csub,
                                                  float alpha) {
    extern __shared__ char ldsc[];   // [buf:2][A 32KB | B 32KB] = 128 KiB
    int tid = threadIdx.x, lane = tid & 63, wv = tid >> 6;
    int q = lane >> 4, l15 = lane & 15;

    // bijective XCD swizzle: 384 blocks % 8 == 0
    int flat = blockIdx.y * 48 + blockIdx.x;
    int swz = (flat & 7) * 48 + (flat >> 3);
    int bx = swz % 48, by = swz / 48;
    int j0g = bx * 256, m0g = by * 256;

    int wmw = (wv >> 2) * 128;       // wave m offset in tile
    int wnw = (wv & 3) * 64;         // wave j offset in tile

    // ---- staging bases: inverse-swizzled global source, linear LDS dest ----
    int srow = tid >> 3;                                   // row within half-tile (0..63)
    int scol = ((tid & 7) * 16) ^ ((srow & 7) << 4);       // swizzled byte col in k-row
    const char* srcA0 = (const char*)Am + (size_t)(m0g + srow) * 4096 + scol;
    const char* srcB0 = (const char*)Bt + (size_t)(j0g + srow) * 4096 + scol;
    char* dstA0 = ldsc + tid * 16;
    char* dstB0 = ldsc + 32768 + tid * 16;

// half-tile = 128 rows x 128 B = 16 KiB = 2 loads/thread (rows +0 / +64)
#define STAGE_A(nb, kt, h)                                                                  \
    do {                                                                                    \
        async_cp16(srcA0 + (size_t)(kt) * 128 + (h) * 524288,                               \
                   dstA0 + (nb) * 65536 + (h) * 16384);                                     \
        async_cp16(srcA0 + (size_t)(kt) * 128 + (h) * 524288 + 262144,                      \
                   dstA0 + (nb) * 65536 + (h) * 16384 + 8192);                              \
    } while (0)
#define STAGE_B(nb, kt, h)                                                                  \
    do {                                                                                    \
        async_cp16(srcB0 + (size_t)(kt) * 128 + (h) * 524288,                               \
                   dstB0 + (nb) * 65536 + (h) * 16384);                                     \
        async_cp16(srcB0 + (size_t)(kt) * 128 + (h) * 524288 + 262144,                      \
                   dstB0 + (nb) * 65536 + (h) * 16384 + 8192);                              \
    } while (0)

    // ---- read-side swizzled column offsets (per lane, constant all tiles) ----
    int rsw = (l15 & 7) << 4;                 // row&7 == l15&7 for every fragment row
    int colh0 = (q * 16) ^ rsw;               // k-half 0
    int colh1 = colh0 ^ 64;                   // k-half 1 (bit 6 flips cleanly under XOR)
    int arA = (wmw + l15) * 128;
    int arB = (wnw + l15) * 128;

    f32x4 acc[8][4];
#pragma unroll
    for (int a = 0; a < 8; ++a)
#pragma unroll
        for (int b = 0; b < 4; ++b) acc[a][b] = (f32x4){0.f, 0.f, 0.f, 0.f};

    // ---- prologue: tile0 {A0,A1,B0,B1} -> buf0, tile1 {B0,B1} -> buf1 ----
    STAGE_A(0, 0, 0);
    STAGE_A(0, 0, 1);
    STAGE_B(0, 0, 0);
    STAGE_B(0, 0, 1);
    STAGE_B(1, 1, 0);
    STAGE_B(1, 1, 1);
    asm volatile("s_waitcnt vmcnt(4)" ::: "memory");   // tile0 landed; t1.B in flight
    __builtin_amdgcn_s_barrier();
    __builtin_amdgcn_sched_barrier(0);

    int cur = 0;
    for (int t = 0; t < NTK; ++t, cur ^= 1) {
        const int nb = cur ^ 1;
        const char* pa = ldsc + (cur << 16);
        const char* pA0 = pa + arA;
        const char* pB0 = pa + 32768 + arB;

        short8 af[4][2], bf0[2][2], bf1[2][2];

        // ---- phase 0: read A[m0] + B[n0]; stage (t+1).A0 -> other buf ----
#pragma unroll
        for (int tm = 0; tm < 4; ++tm) {
            af[tm][0] = *(const short8*)(pA0 + tm * 2048 + colh0);
            af[tm][1] = *(const short8*)(pA0 + tm * 2048 + colh1);
        }
#pragma unroll
        for (int tn = 0; tn < 2; ++tn) {
            bf0[tn][0] = *(const short8*)(pB0 + tn * 2048 + colh0);
            bf0[tn][1] = *(const short8*)(pB0 + tn * 2048 + colh1);
        }
        if (t + 1 < NTK) STAGE_A(nb, t + 1, 0);
        phase_barrier();
        mfma_quad<0, 0>(acc, af, bf0);
        phase_barrier();

        // ---- phase 1: read B[n1]; stage (t+1).A1 -> other buf ----
#pragma unroll
        for (int tn = 0; tn < 2; ++tn) {
            bf1[tn][0] = *(const short8*)(pB0 + 4096 + tn * 2048 + colh0);
            bf1[tn][1] = *(const short8*)(pB0 + 4096 + tn * 2048 + colh1);
        }
        if (t + 1 < NTK) STAGE_A(nb, t + 1, 1);
        phase_barrier();
        mfma_quad<0, 2>(acc, af, bf1);
        phase_barrier();

        // ---- phase 2: read A[m1]; stage (t+2).B0 -> current buf (B reads done) ----
#pragma unroll
        for (int tm = 0; tm < 4; ++tm) {
            af[tm][0] = *(const short8*)(pA0 + 8192 + tm * 2048 + colh0);
            af[tm][1] = *(const short8*)(pA0 + 8192 + tm * 2048 + colh1);
        }
        if (t + 2 < NTK) STAGE_B(cur, t + 2, 0);
        phase_barrier();
        mfma_quad<4, 2>(acc, af, bf1);
        phase_barrier();

        // ---- phase 3: no reads; stage (t+2).B1 -> current buf; tile-end wait ----
        if (t + 2 < NTK) STAGE_B(cur, t + 2, 1);
        phase_barrier();
        mfma_quad<4, 0>(acc, af, bf0);
        asm volatile("" ::: "memory");
        if (t + 2 < NTK) {
            asm volatile("s_waitcnt vmcnt(4)" ::: "memory");  // t+1 fully landed; (t+2).B in flight
        } else if (t + 1 < NTK) {
            asm volatile("s_waitcnt vmcnt(0)" ::: "memory");  // tail: drain everything
        }
        __builtin_amdgcn_s_barrier();
        __builtin_amdgcn_sched_barrier(0);
    }
#undef STAGE_A
#undef STAGE_B

    // ---- epilogue: Out[m][j] bf16,  alpha*acc (- Csub) ----
#pragma unroll
    for (int a = 0; a < 8; ++a) {
        int mbase = m0g + wmw + (a >> 2) * 64 + (a & 3) * 16 + q * 4;
#pragma unroll
        for (int b = 0; b < 4; ++b) {
            int jj = j0g + wnw + (b >> 1) * 32 + (b & 1) * 16 + l15;
#pragma unroll
            for (int r = 0; r < 4; ++r) {
                size_t oidx = (size_t)(mbase + r) * JJ + jj;
                float v = alpha * acc[a][b][r];
                if (Csub) v -= bf2f(Csub[oidx]);
                Out[oidx] = f2bf(v);
            }
        }
    }
}

// ---------------- K5/K6: per-node [192 x 192] @ [192 x 64] MFMA GEMM ----------------
__global__ __launch_bounds__(256) void k_node(const unsigned short* __restrict__ S0,
                                              const unsigned short* __restrict__ S1,
                                              const unsigned short* __restrict__ S2,
                                              const float* __restrict__ E,
                                              const float* __restrict__ Wp,
                                              const float* __restrict__ bias_pool,
                                              const float* __restrict__ mlp_w,
                                              const float* __restrict__ mlp_b,
                                              float* __restrict__ out,
                                              int branch) {
    int n = blockIdx.x, tid = threadIdx.x, lane = tid & 63, wv = tid >> 6;
    __shared__ __align__(16) unsigned short lW[64 * 200];   // W^T: [o][kappa] pad->200
    __shared__ __align__(16) unsigned short lS[192 * 72];   // one source: [m][i] pad->72
    __shared__ float lBias[64];
    int q = lane >> 4, l15 = lane & 15;

    if (branch == 0) {
        float en[ED];
#pragma unroll
        for (int d = 0; d < ED; ++d) en[d] = E[n * ED + d];
        for (int idx = tid; idx < KC * OO; idx += 256) {
            int o = idx & 63, kap = idx >> 6;                  // kap = k*64+i
            float s = 0.f;
#pragma unroll
            for (int d = 0; d < ED; ++d) s += en[d] * Wp[((size_t)d * KC + kap) * OO + o];
            lW[o * 200 + kap] = f2bf(s);
        }
        if (tid < 64) {
            float s = 0.f;
#pragma unroll
            for (int d = 0; d < ED; ++d) s += en[d] * bias_pool[d * OO + tid];
            lBias[tid] = s;
        }
    } else {
        for (int idx = tid; idx < KC * OO; idx += 256) {
            int o = idx & 63, kap = idx >> 6;
            lW[o * 200 + kap] = f2bf(mlp_w[kap * OO + o]);
        }
        if (tid < 64) lBias[tid] = mlp_b[tid];
    }

    f32x4 zero = {0.f, 0.f, 0.f, 0.f};
    f32x4 acc[3][4];
#pragma unroll
    for (int a = 0; a < 3; ++a)
#pragma unroll
        for (int b = 0; b < 4; ++b) acc[a][b] = zero;

    const unsigned short* Ss[3] = { S0 + (size_t)n * JJ, S1 + (size_t)n * JJ, S2 + (size_t)n * JJ };

    for (int s = 0; s < 3; ++s) {
        __syncthreads();
        // stage source row: 12288 bf16 -> lS[m][i] (pad 72)
#pragma unroll
        for (int v = 0; v < 6; ++v) {
            int e8 = (v * 256 + tid) * 8;
            int m = e8 >> 6, i = e8 & 63;
            *(short8*)&lS[m * 72 + i] = *(const short8*)&Ss[s][e8];
        }
        __syncthreads();
#pragma unroll
        for (int h = 0; h < 2; ++h) {
            short8 af[3], bfr[4];
#pragma unroll
            for (int tm = 0; tm < 3; ++tm)
                af[tm] = *(const short8*)&lS[(wv * 48 + tm * 16 + l15) * 72 + h * 32 + q * 8];
#pragma unroll
            for (int tn = 0; tn < 4; ++tn)
                bfr[tn] = *(const short8*)&lW[(tn * 16 + l15) * 200 + s * 64 + h * 32 + q * 8];
#pragma unroll
            for (int tm = 0; tm < 3; ++tm)
#pragma unroll
                for (int tn = 0; tn < 4; ++tn)
                    acc[tm][tn] = __builtin_amdgcn_mfma_f32_16x16x32_bf16(af[tm], bfr[tn], acc[tm][tn], 0, 0, 0);
        }
    }
    // epilogue: out[b][o][n][t] fp32, m = b*T+t
#pragma unroll
    for (int tm = 0; tm < 3; ++tm) {
#pragma unroll
        for (int tn = 0; tn < 4; ++tn) {
            int o = tn * 16 + l15;
#pragma unroll
            for (int r = 0; r < 4; ++r) {
                int m = wv * 48 + tm * 16 + q * 4 + r;
                int b = m / TT, t = m - b * TT;
                out[(((size_t)b * OO + o) * NN + n) * TT + t] = acc[tm][tn][r] + lBias[o];
            }
        }
    }
}

// ---------------- launch ----------------
extern "C" void kernel_launch(void* const* d_in, const int* in_sizes, int n_in,
                              void* d_out, int out_size, void* d_ws, size_t ws_size,
                              hipStream_t stream) {
    const float* x         = (const float*)d_in[0];
    const float* node_emb  = (const float*)d_in[1];
    const float* support   = (const float*)d_in[2];
    const float* wpool     = (const float*)d_in[3];
    const float* bpool     = (const float*)d_in[4];
    const float* mlp_w     = (const float*)d_in[5];
    const float* mlp_b     = (const float*)d_in[6];
    float* out             = (float*)d_out;

    // workspace map (256 MB exactly):
    unsigned short* Abf = (unsigned short*)d_ws;                 // 8 MB
    unsigned short* Atb = Abf + (size_t)NN * NN;                 // 8 MB
    unsigned short* b1  = Atb + (size_t)NN * NN;                 // X2t          [j][n]
    unsigned short* b2  = b1 + (size_t)NJ;                       // X2           [n][j]
    unsigned short* b3  = b2 + (size_t)NJ;                       // Y1t / Z1t    [j][n]
    unsigned short* b4  = b3 + (size_t)NJ;                       // Y1 / Z1      [n][j]
    unsigned short* b5  = b4 + (size_t)NJ;                       // Y2 / Z2      [n][j]

    static int attr_done = 0;
    if (!attr_done) {
        hipFuncSetAttribute(reinterpret_cast<const void*>(k_gemm8),
                            hipFuncAttributeMaxDynamicSharedMemorySize, 131072);
        attr_done = 1;
    }

    dim3 gg8(48, 8);                 // 256x256 tiles over [2048][12288]
    dim3 gt(192, 32);                // transpose grid (64x64 tiles)

    // prep
    k_softmax_A<<<NN, 256, 0, stream>>>(node_emb, Abf);
    k_trans_bf<<<dim3(64, 64), dim3(32, 8), 0, stream>>>(support, Atb);
    k_make_X2<<<NJ / 256, 256, 0, stream>>>(x, b2);              // X2 [n][j]
    k_trans16<<<gt, 256, 0, stream>>>(b2, b1);                   // X2t [j][n]

    // adaptive branch
    k_gemm8<<<gg8, 512, 131072, stream>>>(Abf, b1, b4, nullptr, 1.0f);  // Y1 = A*X2
    k_trans16<<<gt, 256, 0, stream>>>(b4, b3);                          // Y1t
    k_gemm8<<<gg8, 512, 131072, stream>>>(Abf, b3, b5, b2, 2.0f);       // Y2 = 2*A*Y1 - X2
    k_node<<<NN, 256, 0, stream>>>(b2, b4, b5, node_emb, wpool, bpool, nullptr, nullptr,
                                   out, 0);

    // diffusion branch (reuses b3/b4/b5)
    k_gemm8<<<gg8, 512, 131072, stream>>>(Atb, b1, b4, nullptr, 1.0f);  // Z1 = At*X2
    k_trans16<<<gt, 256, 0, stream>>>(b4, b3);                          // Z1t
    k_gemm8<<<gg8, 512, 131072, stream>>>(Atb, b3, b5, nullptr, 1.0f);  // Z2 = At*Z1
    k_node<<<NN, 256, 0, stream>>>(b2, b4, b5, nullptr, nullptr, nullptr, mlp_w, mlp_b,
                                   out + (size_t)NJ, 1);
}

// Round 2
// 1088.400 us; speedup vs baseline: 1.0250x; 1.0121x over previous
//
#include <hip/hip_runtime.h>
#include <stdint.h>

// ---------------- constants ----------------
#define NN    2048          // nodes
#define BB    16            // batch
#define CC    64            // in channels
#define TT    12            // time
#define OO    64            // out channels
#define ED    10            // embed dim
#define JJ    12288         // B*T*C  (j = (b*T+t)*C + c)
#define NJ    25165824      // NN*JJ
#define KC    192           // 3*C contraction of per-node GEMM
#define NTK   32            // K-tiles in the big GEMM (2048 / 64)

typedef __attribute__((ext_vector_type(8))) short short8;   // 8 bf16 = 4 VGPR
typedef __attribute__((ext_vector_type(4))) float f32x4;

__device__ __forceinline__ unsigned short f2bf(float x) {
    union { float f; unsigned int u; } v; v.f = x;
    unsigned int r = (v.u + 0x7FFFu + ((v.u >> 16) & 1u)) >> 16;
    return (unsigned short)r;
}
__device__ __forceinline__ float bf2f(unsigned short h) {
    union { unsigned int u; float f; } v; v.u = ((unsigned int)h) << 16;
    return v.f;
}
__device__ __forceinline__ void async_cp16(const void* g, void* l) {
    __builtin_amdgcn_global_load_lds(
        (const __attribute__((address_space(1))) void*)(uintptr_t)g,
        (__attribute__((address_space(3))) void*)(uintptr_t)l, 16, 0, 0);
}

// raw barrier: NO vmcnt drain, NO sched_barrier (m141: order-pinning kills perf)
__device__ __forceinline__ void phase_barrier() {
    asm volatile("" ::: "memory");
    __builtin_amdgcn_s_barrier();
    asm volatile("" ::: "memory");
}

// ---------------- K1: A = softmax(relu(E E^T)) row-wise -> bf16 ----------------
__global__ __launch_bounds__(256) void k_softmax_A(const float* __restrict__ E,
                                                   unsigned short* __restrict__ Abf) {
    int n = blockIdx.x, tid = threadIdx.x;
    __shared__ float row[NN];
    __shared__ float red[256];
    float en[ED];
#pragma unroll
    for (int d = 0; d < ED; ++d) en[d] = E[n * ED + d];
    float mx = 0.0f;  // relu => values >= 0
    for (int m = tid; m < NN; m += 256) {
        float s = 0.f;
#pragma unroll
        for (int d = 0; d < ED; ++d) s += en[d] * E[m * ED + d];
        s = fmaxf(s, 0.0f);
        row[m] = s;
        mx = fmaxf(mx, s);
    }
    red[tid] = mx; __syncthreads();
    for (int s = 128; s; s >>= 1) { if (tid < s) red[tid] = fmaxf(red[tid], red[tid + s]); __syncthreads(); }
    mx = red[0]; __syncthreads();
    float sum = 0.f;
    for (int m = tid; m < NN; m += 256) { float e = __expf(row[m] - mx); row[m] = e; sum += e; }
    red[tid] = sum; __syncthreads();
    for (int s = 128; s; s >>= 1) { if (tid < s) red[tid] += red[tid + s]; __syncthreads(); }
    float inv = 1.0f / red[0];
    for (int m = tid; m < NN; m += 256) Abf[(size_t)n * NN + m] = f2bf(row[m] * inv);
}

// ---------------- K2: At[w][v] = support[v][w] -> bf16 ----------------
__global__ void k_trans_bf(const float* __restrict__ src, unsigned short* __restrict__ dst) {
    __shared__ float t[32][33];
    int tx = threadIdx.x, ty = threadIdx.y;     // (32, 8)
    int x0 = blockIdx.x * 32, y0 = blockIdx.y * 32;
#pragma unroll
    for (int i = 0; i < 4; ++i)
        t[ty + i * 8][tx] = src[(size_t)(y0 + ty + i * 8) * NN + x0 + tx];
    __syncthreads();
#pragma unroll
    for (int i = 0; i < 4; ++i)
        dst[(size_t)(x0 + ty + i * 8) * NN + y0 + tx] = f2bf(t[tx][ty + i * 8]);
}

// ---------------- K3: X2[n][(b*T+t)*C+c] = x[b][c][n][t] -> bf16 ----------------
__global__ __launch_bounds__(256) void k_make_X2(const float* __restrict__ x,
                                                 unsigned short* __restrict__ X2) {
    int idx = blockIdx.x * 256 + threadIdx.x;   // < NJ
    int n = idx / JJ;
    int r = idx - n * JJ;
    int bt = r >> 6;
    int c = r & 63;
    int b = bt / TT;
    int t = bt - b * TT;
    X2[idx] = f2bf(x[(((size_t)b * CC + c) * NN + n) * TT + t]);
}

// ---------------- K3b: bf16 tiled transpose  dst[j][n] = src[n][j] ----------------
__global__ __launch_bounds__(256) void k_trans16(const unsigned short* __restrict__ src,
                                                 unsigned short* __restrict__ dst) {
    __shared__ unsigned short t[64][72];     // pad 72 shorts
    int tid = threadIdx.x;
    int j0 = blockIdx.x * 64, n0 = blockIdx.y * 64;
    int r = tid >> 3, c8 = (tid & 7) * 8;    // 32 rows per pass, 8 shorts per thread
#pragma unroll
    for (int it = 0; it < 2; ++it) {
        int rr = r + it * 32;
        *(short8*)&t[rr][c8] = *(const short8*)&src[(size_t)(n0 + rr) * JJ + j0 + c8];
    }
    __syncthreads();
#pragma unroll
    for (int it = 0; it < 2; ++it) {
        int rr = r + it * 32;                // j-row within tile
        unsigned short v[8];
#pragma unroll
        for (int u = 0; u < 8; ++u) v[u] = t[c8 + u][rr];
        *(short8*)&dst[(size_t)(j0 + rr) * NN + n0 + c8] = *(short8*)v;
    }
}

// ---------------- K4: 256x256 phased bf16 MFMA GEMM ----------------
// Out[m][j] = alpha * sum_k Am[m][k] * Bt[j][k]  (- Csub[m][j])
// Am: [2048][2048] row-major (k contig). Bt: [12288][2048] row-major (k contig).
// grid (48, 8) natural order (co-resident blocks on an XCD share ~6 B panels),
// block 512 (8 waves, wave tile 128x64), dynamic LDS 128 KiB.
// Per K-tile: 4 phases x 16 MFMA; raw s_barrier (no vmcnt drain, no sched_barrier);
// one counted s_waitcnt vmcnt(6) per K-tile (3 half-tiles in flight).
// Stagger: A(t+1).h0 @ p3(t-1), A(t+1).h1 @ p0(t), B(t+2).h0 @ p2(t),
// B(t+2).h1 + A(t+2).h0 @ p3(t).  LDS XOR-swizzle col^=(row&7)<<4 applied as
// inverse-swizzled GLOBAL source + swizzled ds_read (DMA dest stays linear).
template <int AOFF, int BOFF>
__device__ __forceinline__ void mfma_quad(f32x4 (&acc)[8][4],
                                          const short8 (&A)[4][2],
                                          const short8 (&B)[2][2]) {
    __builtin_amdgcn_s_setprio(1);
#pragma unroll
    for (int h = 0; h < 2; ++h)          // h outermost: 8 independent accs between deps
#pragma unroll
        for (int tm = 0; tm < 4; ++tm)
#pragma unroll
            for (int tn = 0; tn < 2; ++tn)
                acc[AOFF + tm][BOFF + tn] = __builtin_amdgcn_mfma_f32_16x16x32_bf16(
                    A[tm][h], B[tn][h], acc[AOFF + tm][BOFF + tn], 0, 0, 0);
    __builtin_amdgcn_s_setprio(0);
}

__global__ __launch_bounds__(512, 2) void k_gemm8(const unsigned short* __restrict__ Am,
                                                  const unsigned short* __restrict__ Bt,
                                                  unsigned short* __restrict__ Out,
                                                  const unsigned short* __restrict__ Csub,
                                                  float alpha) {
    extern __shared__ char ldsc[];   // [buf:2][A 32KB | B 32KB] = 128 KiB
    int tid = threadIdx.x, lane = tid & 63, wv = tid >> 6;
    int q = lane >> 4, l15 = lane & 15;

    int j0g = blockIdx.x * 256, m0g = blockIdx.y * 256;   // natural order (no swizzle)

    int wmw = (wv >> 2) * 128;       // wave m offset in tile
    int wnw = (wv & 3) * 64;         // wave j offset in tile

    // ---- staging bases: inverse-swizzled global source, linear LDS dest ----
    int srow = tid >> 3;                                   // row within half-tile (0..63)
    int scol = ((tid & 7) * 16) ^ ((srow & 7) << 4);       // swizzled byte col in k-row
    const char* srcA0 = (const char*)Am + (size_t)(m0g + srow) * 4096 + scol;
    const char* srcB0 = (const char*)Bt + (size_t)(j0g + srow) * 4096 + scol;
    char* dstA0 = ldsc + tid * 16;
    char* dstB0 = ldsc + 32768 + tid * 16;

// half-tile = 128 rows x 128 B = 16 KiB = 2 loads/thread (rows +0 / +64)
#define STAGE_A(nb, kt, h)                                                                  \
    do {                                                                                    \
        async_cp16(srcA0 + (size_t)(kt) * 128 + (h) * 524288,                               \
                   dstA0 + (nb) * 65536 + (h) * 16384);                                     \
        async_cp16(srcA0 + (size_t)(kt) * 128 + (h) * 524288 + 262144,                      \
                   dstA0 + (nb) * 65536 + (h) * 16384 + 8192);                              \
    } while (0)
#define STAGE_B(nb, kt, h)                                                                  \
    do {                                                                                    \
        async_cp16(srcB0 + (size_t)(kt) * 128 + (h) * 524288,                               \
                   dstB0 + (nb) * 65536 + (h) * 16384);                                     \
        async_cp16(srcB0 + (size_t)(kt) * 128 + (h) * 524288 + 262144,                      \
                   dstB0 + (nb) * 65536 + (h) * 16384 + 8192);                              \
    } while (0)

    // ---- read-side swizzled column offsets (per lane, constant all tiles) ----
    int rsw = (l15 & 7) << 4;                 // row&7 == l15&7 for every fragment row
    int colh0 = (q * 16) ^ rsw;               // k-half 0
    int colh1 = colh0 ^ 64;                   // k-half 1 (bit 6 flips cleanly under XOR)
    int arA = (wmw + l15) * 128;
    int arB = (wnw + l15) * 128;

    f32x4 acc[8][4];
#pragma unroll
    for (int a = 0; a < 8; ++a)
#pragma unroll
        for (int b = 0; b < 4; ++b) acc[a][b] = (f32x4){0.f, 0.f, 0.f, 0.f};

    // ---- prologue: tile0 {A,B} -> buf0; tile1 {B, A.h0} -> buf1 ----
    STAGE_A(0, 0, 0);
    STAGE_A(0, 0, 1);
    STAGE_B(0, 0, 0);
    STAGE_B(0, 0, 1);
    STAGE_B(1, 1, 0);
    STAGE_B(1, 1, 1);
    STAGE_A(1, 1, 0);
    asm volatile("s_waitcnt vmcnt(6)" ::: "memory");   // tile0 landed; t1.{B,A.h0} in flight
    __builtin_amdgcn_s_barrier();
    asm volatile("" ::: "memory");

    int cur = 0;
    for (int t = 0; t < NTK; ++t, cur ^= 1) {
        const int nb = cur ^ 1;
        const char* pa = ldsc + (cur << 16);
        const char* pA0 = pa + arA;
        const char* pB0 = pa + 32768 + arB;

        short8 af[4][2], bf0[2][2], bf1[2][2];

        // ---- phase 0: read A[m0] + B[n0]; stage (t+1).A.h1 -> other buf ----
#pragma unroll
        for (int tm = 0; tm < 4; ++tm) {
            af[tm][0] = *(const short8*)(pA0 + tm * 2048 + colh0);
            af[tm][1] = *(const short8*)(pA0 + tm * 2048 + colh1);
        }
#pragma unroll
        for (int tn = 0; tn < 2; ++tn) {
            bf0[tn][0] = *(const short8*)(pB0 + tn * 2048 + colh0);
            bf0[tn][1] = *(const short8*)(pB0 + tn * 2048 + colh1);
        }
        if (t + 1 < NTK) STAGE_A(nb, t + 1, 1);
        phase_barrier();
        mfma_quad<0, 0>(acc, af, bf0);
        phase_barrier();

        // ---- phase 1: read B[n1]; no stage ----
#pragma unroll
        for (int tn = 0; tn < 2; ++tn) {
            bf1[tn][0] = *(const short8*)(pB0 + 4096 + tn * 2048 + colh0);
            bf1[tn][1] = *(const short8*)(pB0 + 4096 + tn * 2048 + colh1);
        }
        phase_barrier();
        mfma_quad<0, 2>(acc, af, bf1);
        phase_barrier();                 // all B-reads of this tile done after this

        // ---- phase 2: read A[m1]; stage (t+2).B.h0 -> current buf ----
#pragma unroll
        for (int tm = 0; tm < 4; ++tm) {
            af[tm][0] = *(const short8*)(pA0 + 8192 + tm * 2048 + colh0);
            af[tm][1] = *(const short8*)(pA0 + 8192 + tm * 2048 + colh1);
        }
        if (t + 2 < NTK) STAGE_B(cur, t + 2, 0);
        phase_barrier();
        mfma_quad<4, 2>(acc, af, bf1);
        phase_barrier();                 // all A-reads of this tile done after this

        // ---- phase 3: no reads; stage (t+2).B.h1 + (t+2).A.h0; tile-end wait ----
        if (t + 2 < NTK) {
            STAGE_B(cur, t + 2, 1);
            STAGE_A(cur, t + 2, 0);
        }
        mfma_quad<4, 0>(acc, af, bf0);
        asm volatile("" ::: "memory");
        if (t + 2 < NTK) {
            asm volatile("s_waitcnt vmcnt(6)" ::: "memory");  // (t+1) fully landed
        } else if (t + 1 < NTK) {
            asm volatile("s_waitcnt vmcnt(0)" ::: "memory");  // tail: drain everything
        }
        __builtin_amdgcn_s_barrier();
        asm volatile("" ::: "memory");
    }
#undef STAGE_A
#undef STAGE_B

    // ---- epilogue: Out[m][j] bf16,  alpha*acc (- Csub) ----
#pragma unroll
    for (int a = 0; a < 8; ++a) {
        int mbase = m0g + wmw + (a >> 2) * 64 + (a & 3) * 16 + q * 4;
#pragma unroll
        for (int b = 0; b < 4; ++b) {
            int jj = j0g + wnw + (b >> 1) * 32 + (b & 1) * 16 + l15;
#pragma unroll
            for (int r = 0; r < 4; ++r) {
                size_t oidx = (size_t)(mbase + r) * JJ + jj;
                float v = alpha * acc[a][b][r];
                if (Csub) v -= bf2f(Csub[oidx]);
                Out[oidx] = f2bf(v);
            }
        }
    }
}

// ---------------- K5/K6: per-node [192 x 192] @ [192 x 64] MFMA GEMM ----------------
__global__ __launch_bounds__(256) void k_node(const unsigned short* __restrict__ S0,
                                              const unsigned short* __restrict__ S1,
                                              const unsigned short* __restrict__ S2,
                                              const float* __restrict__ E,
                                              const float* __restrict__ Wp,
                                              const float* __restrict__ bias_pool,
                                              const float* __restrict__ mlp_w,
                                              const float* __restrict__ mlp_b,
                                              float* __restrict__ out,
                                              int branch) {
    int n = blockIdx.x, tid = threadIdx.x, lane = tid & 63, wv = tid >> 6;
    __shared__ __align__(16) unsigned short lW[64 * 200];   // W^T: [o][kappa] pad->200
    __shared__ __align__(16) unsigned short lS[192 * 72];   // one source: [m][i] pad->72
    __shared__ float lBias[64];
    int q = lane >> 4, l15 = lane & 15;

    if (branch == 0) {
        float en[ED];
#pragma unroll
        for (int d = 0; d < ED; ++d) en[d] = E[n * ED + d];
        for (int idx = tid; idx < KC * OO; idx += 256) {
            int o = idx & 63, kap = idx >> 6;                  // kap = k*64+i
            float s = 0.f;
#pragma unroll
            for (int d = 0; d < ED; ++d) s += en[d] * Wp[((size_t)d * KC + kap) * OO + o];
            lW[o * 200 + kap] = f2bf(s);
        }
        if (tid < 64) {
            float s = 0.f;
#pragma unroll
            for (int d = 0; d < ED; ++d) s += en[d] * bias_pool[d * OO + tid];
            lBias[tid] = s;
        }
    } else {
        for (int idx = tid; idx < KC * OO; idx += 256) {
            int o = idx & 63, kap = idx >> 6;
            lW[o * 200 + kap] = f2bf(mlp_w[kap * OO + o]);
        }
        if (tid < 64) lBias[tid] = mlp_b[tid];
    }

    f32x4 zero = {0.f, 0.f, 0.f, 0.f};
    f32x4 acc[3][4];
#pragma unroll
    for (int a = 0; a < 3; ++a)
#pragma unroll
        for (int b = 0; b < 4; ++b) acc[a][b] = zero;

    const unsigned short* Ss[3] = { S0 + (size_t)n * JJ, S1 + (size_t)n * JJ, S2 + (size_t)n * JJ };

    for (int s = 0; s < 3; ++s) {
        __syncthreads();
        // stage source row: 12288 bf16 -> lS[m][i] (pad 72)
#pragma unroll
        for (int v = 0; v < 6; ++v) {
            int e8 = (v * 256 + tid) * 8;
            int m = e8 >> 6, i = e8 & 63;
            *(short8*)&lS[m * 72 + i] = *(const short8*)&Ss[s][e8];
        }
        __syncthreads();
#pragma unroll
        for (int h = 0; h < 2; ++h) {
            short8 af[3], bfr[4];
#pragma unroll
            for (int tm = 0; tm < 3; ++tm)
                af[tm] = *(const short8*)&lS[(wv * 48 + tm * 16 + l15) * 72 + h * 32 + q * 8];
#pragma unroll
            for (int tn = 0; tn < 4; ++tn)
                bfr[tn] = *(const short8*)&lW[(tn * 16 + l15) * 200 + s * 64 + h * 32 + q * 8];
#pragma unroll
            for (int tm = 0; tm < 3; ++tm)
#pragma unroll
                for (int tn = 0; tn < 4; ++tn)
                    acc[tm][tn] = __builtin_amdgcn_mfma_f32_16x16x32_bf16(af[tm], bfr[tn], acc[tm][tn], 0, 0, 0);
        }
    }
    // epilogue: out[b][o][n][t] fp32, m = b*T+t
#pragma unroll
    for (int tm = 0; tm < 3; ++tm) {
#pragma unroll
        for (int tn = 0; tn < 4; ++tn) {
            int o = tn * 16 + l15;
#pragma unroll
            for (int r = 0; r < 4; ++r) {
                int m = wv * 48 + tm * 16 + q * 4 + r;
                int b = m / TT, t = m - b * TT;
                out[(((size_t)b * OO + o) * NN + n) * TT + t] = acc[tm][tn][r] + lBias[o];
            }
        }
    }
}

// ---------------- launch ----------------
extern "C" void kernel_launch(void* const* d_in, const int* in_sizes, int n_in,
                              void* d_out, int out_size, void* d_ws, size_t ws_size,
                              hipStream_t stream) {
    const float* x         = (const float*)d_in[0];
    const float* node_emb  = (const float*)d_in[1];
    const float* support   = (const float*)d_in[2];
    const float* wpool     = (const float*)d_in[3];
    const float* bpool     = (const float*)d_in[4];
    const float* mlp_w     = (const float*)d_in[5];
    const float* mlp_b     = (const float*)d_in[6];
    float* out             = (float*)d_out;

    // workspace map (256 MB exactly):
    unsigned short* Abf = (unsigned short*)d_ws;                 // 8 MB
    unsigned short* Atb = Abf + (size_t)NN * NN;                 // 8 MB
    unsigned short* b1  = Atb + (size_t)NN * NN;                 // X2t          [j][n]
    unsigned short* b2  = b1 + (size_t)NJ;                       // X2           [n][j]
    unsigned short* b3  = b2 + (size_t)NJ;                       // Y1t / Z1t    [j][n]
    unsigned short* b4  = b3 + (size_t)NJ;                       // Y1 / Z1      [n][j]
    unsigned short* b5  = b4 + (size_t)NJ;                       // Y2 / Z2      [n][j]

    static int attr_done = 0;
    if (!attr_done) {
        hipFuncSetAttribute(reinterpret_cast<const void*>(k_gemm8),
                            hipFuncAttributeMaxDynamicSharedMemorySize, 131072);
        attr_done = 1;
    }

    dim3 gg8(48, 8);                 // 256x256 tiles over [2048][12288]
    dim3 gt(192, 32);                // transpose grid (64x64 tiles)

    // prep
    k_softmax_A<<<NN, 256, 0, stream>>>(node_emb, Abf);
    k_trans_bf<<<dim3(64, 64), dim3(32, 8), 0, stream>>>(support, Atb);
    k_make_X2<<<NJ / 256, 256, 0, stream>>>(x, b2);              // X2 [n][j]
    k_trans16<<<gt, 256, 0, stream>>>(b2, b1);                   // X2t [j][n]

    // adaptive branch
    k_gemm8<<<gg8, 512, 131072, stream>>>(Abf, b1, b4, nullptr, 1.0f);  // Y1 = A*X2
    k_trans16<<<gt, 256, 0, stream>>>(b4, b3);                          // Y1t
    k_gemm8<<<gg8, 512, 131072, stream>>>(Abf, b3, b5, b2, 2.0f);       // Y2 = 2*A*Y1 - X2
    k_node<<<NN, 256, 0, stream>>>(b2, b4, b5, node_emb, wpool, bpool, nullptr, nullptr,
                                   out, 0);

    // diffusion branch (reuses b3/b4/b5)
    k_gemm8<<<gg8, 512, 131072, stream>>>(Atb, b1, b4, nullptr, 1.0f);  // Z1 = At*X2
    k_trans16<<<gt, 256, 0, stream>>>(b4, b3);                          // Z1t
    k_gemm8<<<gg8, 512, 131072, stream>>>(Atb, b3, b5, nullptr, 1.0f);  // Z2 = At*Z1
    k_node<<<NN, 256, 0, stream>>>(b2, b4, b5, nullptr, nullptr, nullptr, mlp_w, mlp_b,
                                   out + (size_t)NJ, 1);
}

// Round 3
// 1082.003 us; speedup vs baseline: 1.0311x; 1.0059x over previous
//
#include <hip/hip_runtime.h>
#include <stdint.h>

// ---------------- constants ----------------
#define NN    2048          // nodes
#define BB    16            // batch
#define CC    64            // in channels
#define TT    12            // time
#define OO    64            // out channels
#define ED    10            // embed dim
#define JJ    12288         // B*T*C  (j = (b*T+t)*C + c)
#define NJ    25165824      // NN*JJ
#define KC    192           // 3*C contraction of per-node GEMM
#define NTK   32            // K-tiles in the big GEMM (2048 / 64)

typedef __attribute__((ext_vector_type(8))) short short8;   // 8 bf16 = 4 VGPR
typedef __attribute__((ext_vector_type(4))) float f32x4;

__device__ __forceinline__ unsigned short f2bf(float x) {
    union { float f; unsigned int u; } v; v.f = x;
    unsigned int r = (v.u + 0x7FFFu + ((v.u >> 16) & 1u)) >> 16;
    return (unsigned short)r;
}
__device__ __forceinline__ float bf2f(unsigned short h) {
    union { unsigned int u; float f; } v; v.u = ((unsigned int)h) << 16;
    return v.f;
}
__device__ __forceinline__ void async_cp16(const void* g, void* l) {
    __builtin_amdgcn_global_load_lds(
        (const __attribute__((address_space(1))) void*)(uintptr_t)g,
        (__attribute__((address_space(3))) void*)(uintptr_t)l, 16, 0, 0);
}

// ---------------- K1: A = softmax(relu(E E^T)) row-wise -> bf16 ----------------
__global__ __launch_bounds__(256) void k_softmax_A(const float* __restrict__ E,
                                                   unsigned short* __restrict__ Abf) {
    int n = blockIdx.x, tid = threadIdx.x;
    __shared__ float row[NN];
    __shared__ float red[256];
    float en[ED];
#pragma unroll
    for (int d = 0; d < ED; ++d) en[d] = E[n * ED + d];
    float mx = 0.0f;  // relu => values >= 0
    for (int m = tid; m < NN; m += 256) {
        float s = 0.f;
#pragma unroll
        for (int d = 0; d < ED; ++d) s += en[d] * E[m * ED + d];
        s = fmaxf(s, 0.0f);
        row[m] = s;
        mx = fmaxf(mx, s);
    }
    red[tid] = mx; __syncthreads();
    for (int s = 128; s; s >>= 1) { if (tid < s) red[tid] = fmaxf(red[tid], red[tid + s]); __syncthreads(); }
    mx = red[0]; __syncthreads();
    float sum = 0.f;
    for (int m = tid; m < NN; m += 256) { float e = __expf(row[m] - mx); row[m] = e; sum += e; }
    red[tid] = sum; __syncthreads();
    for (int s = 128; s; s >>= 1) { if (tid < s) red[tid] += red[tid + s]; __syncthreads(); }
    float inv = 1.0f / red[0];
    for (int m = tid; m < NN; m += 256) Abf[(size_t)n * NN + m] = f2bf(row[m] * inv);
}

// ---------------- K2: At[w][v] = support[v][w] -> bf16 ----------------
__global__ void k_trans_bf(const float* __restrict__ src, unsigned short* __restrict__ dst) {
    __shared__ float t[32][33];
    int tx = threadIdx.x, ty = threadIdx.y;     // (32, 8)
    int x0 = blockIdx.x * 32, y0 = blockIdx.y * 32;
#pragma unroll
    for (int i = 0; i < 4; ++i)
        t[ty + i * 8][tx] = src[(size_t)(y0 + ty + i * 8) * NN + x0 + tx];
    __syncthreads();
#pragma unroll
    for (int i = 0; i < 4; ++i)
        dst[(size_t)(x0 + ty + i * 8) * NN + y0 + tx] = f2bf(t[tx][ty + i * 8]);
}

// ---------------- K3: X2[n][(b*T+t)*C+c] = x[b][c][n][t] -> bf16 ----------------
__global__ __launch_bounds__(256) void k_make_X2(const float* __restrict__ x,
                                                 unsigned short* __restrict__ X2) {
    int idx = blockIdx.x * 256 + threadIdx.x;   // < NJ
    int n = idx / JJ;
    int r = idx - n * JJ;
    int bt = r >> 6;
    int c = r & 63;
    int b = bt / TT;
    int t = bt - b * TT;
    X2[idx] = f2bf(x[(((size_t)b * CC + c) * NN + n) * TT + t]);
}

// ---------------- K3b: bf16 tiled transpose  dst[j][n] = src[n][j] ----------------
__global__ __launch_bounds__(256) void k_trans16(const unsigned short* __restrict__ src,
                                                 unsigned short* __restrict__ dst) {
    __shared__ unsigned short t[64][72];     // pad 72 shorts
    int tid = threadIdx.x;
    int j0 = blockIdx.x * 64, n0 = blockIdx.y * 64;
    int r = tid >> 3, c8 = (tid & 7) * 8;    // 32 rows per pass, 8 shorts per thread
#pragma unroll
    for (int it = 0; it < 2; ++it) {
        int rr = r + it * 32;
        *(short8*)&t[rr][c8] = *(const short8*)&src[(size_t)(n0 + rr) * JJ + j0 + c8];
    }
    __syncthreads();
#pragma unroll
    for (int it = 0; it < 2; ++it) {
        int rr = r + it * 32;                // j-row within tile
        unsigned short v[8];
#pragma unroll
        for (int u = 0; u < 8; ++u) v[u] = t[c8 + u][rr];
        *(short8*)&dst[(size_t)(j0 + rr) * NN + n0 + c8] = *(short8*)v;
    }
}

// ---------------- K4: 256x256 bf16 MFMA GEMM, 2 hazard-barriers per K-tile ----------------
// Out[m][j] = alpha * sum_k Am[m][k] * Bt[j][k]  (- Csub[m][j])
// Am: [2048][2048] row-major (k contig). Bt: [12288][2048] row-major (k contig).
// grid (48, 8) natural order, block 512 (8 waves, wave tile 128x64), LDS 128 KiB.
// Per K-tile: NO barrier between ds_reads and MFMA (that serialized LDS pipe vs
// MFMA pipe CU-wide -> 24% MfmaUtil plateau). Only the two true hazards sync:
//   barrier#1: B-frag ds_reads complete  -> then STAGE_B(cur, t+2) may overwrite
//   barrier#2 (boundary): all reads complete + vmcnt(4) counted (t+1 landed,
//              B(t+2) still in flight -- never drain to 0 in the loop).
// A(t+1) staged at tile top into the other buffer (no hazard: nobody reads it).
// LDS XOR-swizzle col^=(row&7)<<4 via inverse-swizzled GLOBAL source + swizzled
// ds_read (DMA dest stays linear). Explicit lgkmcnt(0) before each barrier:
// completion must not rely on MFMA consumption (compiler may sink MFMAs, rule 18).
template <int AOFF, int BOFF>
__device__ __forceinline__ void mfma_quad(f32x4 (&acc)[8][4],
                                          const short8 (&A)[4][2],
                                          const short8 (&B)[2][2]) {
    __builtin_amdgcn_s_setprio(1);
#pragma unroll
    for (int h = 0; h < 2; ++h)          // h outermost: 8 independent accs between deps
#pragma unroll
        for (int tm = 0; tm < 4; ++tm)
#pragma unroll
            for (int tn = 0; tn < 2; ++tn)
                acc[AOFF + tm][BOFF + tn] = __builtin_amdgcn_mfma_f32_16x16x32_bf16(
                    A[tm][h], B[tn][h], acc[AOFF + tm][BOFF + tn], 0, 0, 0);
    __builtin_amdgcn_s_setprio(0);
}

__global__ __launch_bounds__(512, 2) void k_gemm8(const unsigned short* __restrict__ Am,
                                                  const unsigned short* __restrict__ Bt,
                                                  unsigned short* __restrict__ Out,
                                                  const unsigned short* __restrict__ Csub,
                                                  float alpha) {
    extern __shared__ char ldsc[];   // [buf:2][A 32KB | B 32KB] = 128 KiB
    int tid = threadIdx.x, lane = tid & 63, wv = tid >> 6;
    int q = lane >> 4, l15 = lane & 15;

    int j0g = blockIdx.x * 256, m0g = blockIdx.y * 256;   // natural order

    int wmw = (wv >> 2) * 128;       // wave m offset in tile
    int wnw = (wv & 3) * 64;         // wave j offset in tile

    // ---- staging bases: inverse-swizzled global source, linear LDS dest ----
    int srow = tid >> 3;                                   // row within half-tile (0..63)
    int scol = ((tid & 7) * 16) ^ ((srow & 7) << 4);       // swizzled byte col in k-row
    const char* srcA0 = (const char*)Am + (size_t)(m0g + srow) * 4096 + scol;
    const char* srcB0 = (const char*)Bt + (size_t)(j0g + srow) * 4096 + scol;
    char* dstA0 = ldsc + tid * 16;
    char* dstB0 = ldsc + 32768 + tid * 16;

// half-tile = 128 rows x 128 B = 16 KiB = 2 loads/thread (rows +0 / +64)
#define STAGE_A(nb, kt, h)                                                                  \
    do {                                                                                    \
        async_cp16(srcA0 + (size_t)(kt) * 128 + (h) * 524288,                               \
                   dstA0 + (nb) * 65536 + (h) * 16384);                                     \
        async_cp16(srcA0 + (size_t)(kt) * 128 + (h) * 524288 + 262144,                      \
                   dstA0 + (nb) * 65536 + (h) * 16384 + 8192);                              \
    } while (0)
#define STAGE_B(nb, kt, h)                                                                  \
    do {                                                                                    \
        async_cp16(srcB0 + (size_t)(kt) * 128 + (h) * 524288,                               \
                   dstB0 + (nb) * 65536 + (h) * 16384);                                     \
        async_cp16(srcB0 + (size_t)(kt) * 128 + (h) * 524288 + 262144,                      \
                   dstB0 + (nb) * 65536 + (h) * 16384 + 8192);                              \
    } while (0)

    // ---- read-side swizzled column offsets (per lane, constant all tiles) ----
    int rsw = (l15 & 7) << 4;                 // row&7 == l15&7 for every fragment row
    int colh0 = (q * 16) ^ rsw;               // k-half 0
    int colh1 = colh0 ^ 64;                   // k-half 1 (bit 6 flips cleanly under XOR)
    int arA = (wmw + l15) * 128;
    int arB = (wnw + l15) * 128;

    f32x4 acc[8][4];
#pragma unroll
    for (int a = 0; a < 8; ++a)
#pragma unroll
        for (int b = 0; b < 4; ++b) acc[a][b] = (f32x4){0.f, 0.f, 0.f, 0.f};

    // ---- prologue: tile0 {A,B} -> buf0 (8 loads); t1.B -> buf1 (4 loads) ----
    STAGE_A(0, 0, 0);
    STAGE_A(0, 0, 1);
    STAGE_B(0, 0, 0);
    STAGE_B(0, 0, 1);
    STAGE_B(1, 1, 0);
    STAGE_B(1, 1, 1);
    asm volatile("s_waitcnt vmcnt(4)" ::: "memory");   // tile0 landed; t1.B in flight
    __builtin_amdgcn_s_barrier();
    asm volatile("" ::: "memory");

    int cur = 0;
    for (int t = 0; t < NTK; ++t, cur ^= 1) {
        const int nb = cur ^ 1;
        const char* pa = ldsc + (cur << 16);
        const char* pA0 = pa + arA;
        const char* pB0 = pa + 32768 + arB;

        // ---- top: stage (t+1).A into other buffer (no hazard: nb not read now) ----
        if (t + 1 < NTK) {
            STAGE_A(nb, t + 1, 0);
            STAGE_A(nb, t + 1, 1);
        }

        short8 af[4][2], bf0[2][2], bf1[2][2];

        // ---- first half: read A[m0] + all B, MFMA 2 quads (no barrier inside) ----
#pragma unroll
        for (int tm = 0; tm < 4; ++tm) {
            af[tm][0] = *(const short8*)(pA0 + tm * 2048 + colh0);
            af[tm][1] = *(const short8*)(pA0 + tm * 2048 + colh1);
        }
#pragma unroll
        for (int tn = 0; tn < 2; ++tn) {
            bf0[tn][0] = *(const short8*)(pB0 + tn * 2048 + colh0);
            bf0[tn][1] = *(const short8*)(pB0 + tn * 2048 + colh1);
            bf1[tn][0] = *(const short8*)(pB0 + 4096 + tn * 2048 + colh0);
            bf1[tn][1] = *(const short8*)(pB0 + 4096 + tn * 2048 + colh1);
        }
        mfma_quad<0, 0>(acc, af, bf0);
        mfma_quad<0, 2>(acc, af, bf1);

        // ---- hazard #1: B reads complete -> overwrite cur B with (t+2).B ----
        if (t + 2 < NTK) {
            asm volatile("s_waitcnt lgkmcnt(0)" ::: "memory");
            __builtin_amdgcn_s_barrier();
            asm volatile("" ::: "memory");
            STAGE_B(cur, t + 2, 0);
            STAGE_B(cur, t + 2, 1);
        }

        // ---- second half: read A[m1], MFMA 2 quads (no barrier inside) ----
#pragma unroll
        for (int tm = 0; tm < 4; ++tm) {
            af[tm][0] = *(const short8*)(pA0 + 8192 + tm * 2048 + colh0);
            af[tm][1] = *(const short8*)(pA0 + 8192 + tm * 2048 + colh1);
        }
        mfma_quad<4, 2>(acc, af, bf1);
        mfma_quad<4, 0>(acc, af, bf0);

        // ---- hazard #2 (boundary): all reads done; (t+1) landed; B(t+2) in flight ----
        if (t + 2 < NTK) {
            asm volatile("s_waitcnt vmcnt(4) lgkmcnt(0)" ::: "memory");
            __builtin_amdgcn_s_barrier();
            asm volatile("" ::: "memory");
        } else if (t + 1 < NTK) {
            asm volatile("s_waitcnt vmcnt(0) lgkmcnt(0)" ::: "memory");
            __builtin_amdgcn_s_barrier();
            asm volatile("" ::: "memory");
        }
        // t == NTK-1: fall through to epilogue (registers only)
    }
#undef STAGE_A
#undef STAGE_B

    // ---- epilogue: Out[m][j] bf16,  alpha*acc (- Csub) ----
#pragma unroll
    for (int a = 0; a < 8; ++a) {
        int mbase = m0g + wmw + (a >> 2) * 64 + (a & 3) * 16 + q * 4;
#pragma unroll
        for (int b = 0; b < 4; ++b) {
            int jj = j0g + wnw + (b >> 1) * 32 + (b & 1) * 16 + l15;
#pragma unroll
            for (int r = 0; r < 4; ++r) {
                size_t oidx = (size_t)(mbase + r) * JJ + jj;
                float v = alpha * acc[a][b][r];
                if (Csub) v -= bf2f(Csub[oidx]);
                Out[oidx] = f2bf(v);
            }
        }
    }
}

// ---------------- K5/K6: per-node [192 x 192] @ [192 x 64] MFMA GEMM ----------------
__global__ __launch_bounds__(256) void k_node(const unsigned short* __restrict__ S0,
                                              const unsigned short* __restrict__ S1,
                                              const unsigned short* __restrict__ S2,
                                              const float* __restrict__ E,
                                              const float* __restrict__ Wp,
                                              const float* __restrict__ bias_pool,
                                              const float* __restrict__ mlp_w,
                                              const float* __restrict__ mlp_b,
                                              float* __restrict__ out,
                                              int branch) {
    int n = blockIdx.x, tid = threadIdx.x, lane = tid & 63, wv = tid >> 6;
    __shared__ __align__(16) unsigned short lW[64 * 200];   // W^T: [o][kappa] pad->200
    __shared__ __align__(16) unsigned short lS[192 * 72];   // one source: [m][i] pad->72
    __shared__ float lBias[64];
    int q = lane >> 4, l15 = lane & 15;

    if (branch == 0) {
        float en[ED];
#pragma unroll
        for (int d = 0; d < ED; ++d) en[d] = E[n * ED + d];
        for (int idx = tid; idx < KC * OO; idx += 256) {
            int o = idx & 63, kap = idx >> 6;                  // kap = k*64+i
            float s = 0.f;
#pragma unroll
            for (int d = 0; d < ED; ++d) s += en[d] * Wp[((size_t)d * KC + kap) * OO + o];
            lW[o * 200 + kap] = f2bf(s);
        }
        if (tid < 64) {
            float s = 0.f;
#pragma unroll
            for (int d = 0; d < ED; ++d) s += en[d] * bias_pool[d * OO + tid];
            lBias[tid] = s;
        }
    } else {
        for (int idx = tid; idx < KC * OO; idx += 256) {
            int o = idx & 63, kap = idx >> 6;
            lW[o * 200 + kap] = f2bf(mlp_w[kap * OO + o]);
        }
        if (tid < 64) lBias[tid] = mlp_b[tid];
    }

    f32x4 zero = {0.f, 0.f, 0.f, 0.f};
    f32x4 acc[3][4];
#pragma unroll
    for (int a = 0; a < 3; ++a)
#pragma unroll
        for (int b = 0; b < 4; ++b) acc[a][b] = zero;

    const unsigned short* Ss[3] = { S0 + (size_t)n * JJ, S1 + (size_t)n * JJ, S2 + (size_t)n * JJ };

    for (int s = 0; s < 3; ++s) {
        __syncthreads();
        // stage source row: 12288 bf16 -> lS[m][i] (pad 72)
#pragma unroll
        for (int v = 0; v < 6; ++v) {
            int e8 = (v * 256 + tid) * 8;
            int m = e8 >> 6, i = e8 & 63;
            *(short8*)&lS[m * 72 + i] = *(const short8*)&Ss[s][e8];
        }
        __syncthreads();
#pragma unroll
        for (int h = 0; h < 2; ++h) {
            short8 af[3], bfr[4];
#pragma unroll
            for (int tm = 0; tm < 3; ++tm)
                af[tm] = *(const short8*)&lS[(wv * 48 + tm * 16 + l15) * 72 + h * 32 + q * 8];
#pragma unroll
            for (int tn = 0; tn < 4; ++tn)
                bfr[tn] = *(const short8*)&lW[(tn * 16 + l15) * 200 + s * 64 + h * 32 + q * 8];
#pragma unroll
            for (int tm = 0; tm < 3; ++tm)
#pragma unroll
                for (int tn = 0; tn < 4; ++tn)
                    acc[tm][tn] = __builtin_amdgcn_mfma_f32_16x16x32_bf16(af[tm], bfr[tn], acc[tm][tn], 0, 0, 0);
        }
    }
    // epilogue: out[b][o][n][t] fp32, m = b*T+t
#pragma unroll
    for (int tm = 0; tm < 3; ++tm) {
#pragma unroll
        for (int tn = 0; tn < 4; ++tn) {
            int o = tn * 16 + l15;
#pragma unroll
            for (int r = 0; r < 4; ++r) {
                int m = wv * 48 + tm * 16 + q * 4 + r;
                int b = m / TT, t = m - b * TT;
                out[(((size_t)b * OO + o) * NN + n) * TT + t] = acc[tm][tn][r] + lBias[o];
            }
        }
    }
}

// ---------------- launch ----------------
extern "C" void kernel_launch(void* const* d_in, const int* in_sizes, int n_in,
                              void* d_out, int out_size, void* d_ws, size_t ws_size,
                              hipStream_t stream) {
    const float* x         = (const float*)d_in[0];
    const float* node_emb  = (const float*)d_in[1];
    const float* support   = (const float*)d_in[2];
    const float* wpool     = (const float*)d_in[3];
    const float* bpool     = (const float*)d_in[4];
    const float* mlp_w     = (const float*)d_in[5];
    const float* mlp_b     = (const float*)d_in[6];
    float* out             = (float*)d_out;

    // workspace map (256 MB exactly):
    unsigned short* Abf = (unsigned short*)d_ws;                 // 8 MB
    unsigned short* Atb = Abf + (size_t)NN * NN;                 // 8 MB
    unsigned short* b1  = Atb + (size_t)NN * NN;                 // X2t          [j][n]
    unsigned short* b2  = b1 + (size_t)NJ;                       // X2           [n][j]
    unsigned short* b3  = b2 + (size_t)NJ;                       // Y1t / Z1t    [j][n]
    unsigned short* b4  = b3 + (size_t)NJ;                       // Y1 / Z1      [n][j]
    unsigned short* b5  = b4 + (size_t)NJ;                       // Y2 / Z2      [n][j]

    static int attr_done = 0;
    if (!attr_done) {
        hipFuncSetAttribute(reinterpret_cast<const void*>(k_gemm8),
                            hipFuncAttributeMaxDynamicSharedMemorySize, 131072);
        attr_done = 1;
    }

    dim3 gg8(48, 8);                 // 256x256 tiles over [2048][12288]
    dim3 gt(192, 32);                // transpose grid (64x64 tiles)

    // prep
    k_softmax_A<<<NN, 256, 0, stream>>>(node_emb, Abf);
    k_trans_bf<<<dim3(64, 64), dim3(32, 8), 0, stream>>>(support, Atb);
    k_make_X2<<<NJ / 256, 256, 0, stream>>>(x, b2);              // X2 [n][j]
    k_trans16<<<gt, 256, 0, stream>>>(b2, b1);                   // X2t [j][n]

    // adaptive branch
    k_gemm8<<<gg8, 512, 131072, stream>>>(Abf, b1, b4, nullptr, 1.0f);  // Y1 = A*X2
    k_trans16<<<gt, 256, 0, stream>>>(b4, b3);                          // Y1t
    k_gemm8<<<gg8, 512, 131072, stream>>>(Abf, b3, b5, b2, 2.0f);       // Y2 = 2*A*Y1 - X2
    k_node<<<NN, 256, 0, stream>>>(b2, b4, b5, node_emb, wpool, bpool, nullptr, nullptr,
                                   out, 0);

    // diffusion branch (reuses b3/b4/b5)
    k_gemm8<<<gg8, 512, 131072, stream>>>(Atb, b1, b4, nullptr, 1.0f);  // Z1 = At*X2
    k_trans16<<<gt, 256, 0, stream>>>(b4, b3);                          // Z1t
    k_gemm8<<<gg8, 512, 131072, stream>>>(Atb, b3, b5, nullptr, 1.0f);  // Z2 = At*Z1
    k_node<<<NN, 256, 0, stream>>>(b2, b4, b5, nullptr, nullptr, nullptr, mlp_w, mlp_b,
                                   out + (size_t)NJ, 1);
}

// Round 4
// 1079.640 us; speedup vs baseline: 1.0333x; 1.0022x over previous
//
#include <hip/hip_runtime.h>
#include <stdint.h>

// ---------------- constants ----------------
#define NN    2048          // nodes
#define BB    16            // batch
#define CC    64            // in channels
#define TT    12            // time
#define OO    64            // out channels
#define ED    10            // embed dim
#define JJ    12288         // B*T*C  (j = (b*T+t)*C + c)
#define NJ    25165824      // NN*JJ
#define KC    192           // 3*C contraction of per-node GEMM
#define NTK   32            // K-tiles in the big GEMM (2048 / 64)

typedef __attribute__((ext_vector_type(8))) short short8;   // 8 bf16 = 4 VGPR
typedef __attribute__((ext_vector_type(4))) float f32x4;

__device__ __forceinline__ unsigned short f2bf(float x) {
    union { float f; unsigned int u; } v; v.f = x;
    unsigned int r = (v.u + 0x7FFFu + ((v.u >> 16) & 1u)) >> 16;
    return (unsigned short)r;
}
__device__ __forceinline__ float bf2f(unsigned short h) {
    union { unsigned int u; float f; } v; v.u = ((unsigned int)h) << 16;
    return v.f;
}
__device__ __forceinline__ void async_cp16(const void* g, void* l) {
    __builtin_amdgcn_global_load_lds(
        (const __attribute__((address_space(1))) void*)(uintptr_t)g,
        (__attribute__((address_space(3))) void*)(uintptr_t)l, 16, 0, 0);
}

// ---------------- K1: A = softmax(relu(E E^T)) row-wise -> bf16 ----------------
__global__ __launch_bounds__(256) void k_softmax_A(const float* __restrict__ E,
                                                   unsigned short* __restrict__ Abf) {
    int n = blockIdx.x, tid = threadIdx.x;
    __shared__ float row[NN];
    __shared__ float red[256];
    float en[ED];
#pragma unroll
    for (int d = 0; d < ED; ++d) en[d] = E[n * ED + d];
    float mx = 0.0f;  // relu => values >= 0
    for (int m = tid; m < NN; m += 256) {
        float s = 0.f;
#pragma unroll
        for (int d = 0; d < ED; ++d) s += en[d] * E[m * ED + d];
        s = fmaxf(s, 0.0f);
        row[m] = s;
        mx = fmaxf(mx, s);
    }
    red[tid] = mx; __syncthreads();
    for (int s = 128; s; s >>= 1) { if (tid < s) red[tid] = fmaxf(red[tid], red[tid + s]); __syncthreads(); }
    mx = red[0]; __syncthreads();
    float sum = 0.f;
    for (int m = tid; m < NN; m += 256) { float e = __expf(row[m] - mx); row[m] = e; sum += e; }
    red[tid] = sum; __syncthreads();
    for (int s = 128; s; s >>= 1) { if (tid < s) red[tid] += red[tid + s]; __syncthreads(); }
    float inv = 1.0f / red[0];
    for (int m = tid; m < NN; m += 256) Abf[(size_t)n * NN + m] = f2bf(row[m] * inv);
}

// ---------------- K2: At[w][v] = support[v][w] -> bf16 ----------------
__global__ void k_trans_bf(const float* __restrict__ src, unsigned short* __restrict__ dst) {
    __shared__ float t[32][33];
    int tx = threadIdx.x, ty = threadIdx.y;     // (32, 8)
    int x0 = blockIdx.x * 32, y0 = blockIdx.y * 32;
#pragma unroll
    for (int i = 0; i < 4; ++i)
        t[ty + i * 8][tx] = src[(size_t)(y0 + ty + i * 8) * NN + x0 + tx];
    __syncthreads();
#pragma unroll
    for (int i = 0; i < 4; ++i)
        dst[(size_t)(x0 + ty + i * 8) * NN + y0 + tx] = f2bf(t[tx][ty + i * 8]);
}

// ---------------- K3: X2[n][(b*T+t)*C+c] = x[b][c][n][t] -> bf16 ----------------
__global__ __launch_bounds__(256) void k_make_X2(const float* __restrict__ x,
                                                 unsigned short* __restrict__ X2) {
    int idx = blockIdx.x * 256 + threadIdx.x;   // < NJ
    int n = idx / JJ;
    int r = idx - n * JJ;
    int bt = r >> 6;
    int c = r & 63;
    int b = bt / TT;
    int t = bt - b * TT;
    X2[idx] = f2bf(x[(((size_t)b * CC + c) * NN + n) * TT + t]);
}

// ---------------- K3b: bf16 tiled transpose  dst[j][n] = src[n][j] ----------------
__global__ __launch_bounds__(256) void k_trans16(const unsigned short* __restrict__ src,
                                                 unsigned short* __restrict__ dst) {
    __shared__ unsigned short t[64][72];     // pad 72 shorts
    int tid = threadIdx.x;
    int j0 = blockIdx.x * 64, n0 = blockIdx.y * 64;
    int r = tid >> 3, c8 = (tid & 7) * 8;    // 32 rows per pass, 8 shorts per thread
#pragma unroll
    for (int it = 0; it < 2; ++it) {
        int rr = r + it * 32;
        *(short8*)&t[rr][c8] = *(const short8*)&src[(size_t)(n0 + rr) * JJ + j0 + c8];
    }
    __syncthreads();
#pragma unroll
    for (int it = 0; it < 2; ++it) {
        int rr = r + it * 32;                // j-row within tile
        unsigned short v[8];
#pragma unroll
        for (int u = 0; u < 8; ++u) v[u] = t[c8 + u][rr];
        *(short8*)&dst[(size_t)(j0 + rr) * NN + n0 + c8] = *(short8*)v;
    }
}

// ---------------- K4: 256x256 bf16 MFMA GEMM (z-mergeable) ----------------
// Out[m][j] = alpha * sum_k Am[m][k] * Bt[j][k]  (- Csub[m][j])
// blockIdx.z selects (AmA,OutA) vs (AmB,OutB) so independent GEMMs sharing the
// same B operand merge into one dispatch (768 blocks = 3 exact rounds on 256
// CUs, vs 2x 384-block dispatches at 1.5 rounds each = 25% tail waste per
// dispatch). Inner structure unchanged from R3 (best measured; the per-block
// rate is structure-invariant across R0/R1/R3 -> memory-hierarchy-bound).
template <int AOFF, int BOFF>
__device__ __forceinline__ void mfma_quad(f32x4 (&acc)[8][4],
                                          const short8 (&A)[4][2],
                                          const short8 (&B)[2][2]) {
    __builtin_amdgcn_s_setprio(1);
#pragma unroll
    for (int h = 0; h < 2; ++h)          // h outermost: 8 independent accs between deps
#pragma unroll
        for (int tm = 0; tm < 4; ++tm)
#pragma unroll
            for (int tn = 0; tn < 2; ++tn)
                acc[AOFF + tm][BOFF + tn] = __builtin_amdgcn_mfma_f32_16x16x32_bf16(
                    A[tm][h], B[tn][h], acc[AOFF + tm][BOFF + tn], 0, 0, 0);
    __builtin_amdgcn_s_setprio(0);
}

__global__ __launch_bounds__(512, 2) void k_gemm8(const unsigned short* __restrict__ AmA,
                                                  const unsigned short* __restrict__ AmB,
                                                  const unsigned short* __restrict__ Bt,
                                                  unsigned short* __restrict__ OutA,
                                                  unsigned short* __restrict__ OutB,
                                                  const unsigned short* __restrict__ Csub,
                                                  float alpha) {
    extern __shared__ char ldsc[];   // [buf:2][A 32KB | B 32KB] = 128 KiB
    int tid = threadIdx.x, lane = tid & 63, wv = tid >> 6;
    int q = lane >> 4, l15 = lane & 15;

    const unsigned short* Am = blockIdx.z ? AmB : AmA;
    unsigned short* Out      = blockIdx.z ? OutB : OutA;

    int j0g = blockIdx.x * 256, m0g = blockIdx.y * 256;   // natural order

    int wmw = (wv >> 2) * 128;       // wave m offset in tile
    int wnw = (wv & 3) * 64;         // wave j offset in tile

    // ---- staging bases: inverse-swizzled global source, linear LDS dest ----
    int srow = tid >> 3;                                   // row within half-tile (0..63)
    int scol = ((tid & 7) * 16) ^ ((srow & 7) << 4);       // swizzled byte col in k-row
    const char* srcA0 = (const char*)Am + (size_t)(m0g + srow) * 4096 + scol;
    const char* srcB0 = (const char*)Bt + (size_t)(j0g + srow) * 4096 + scol;
    char* dstA0 = ldsc + tid * 16;
    char* dstB0 = ldsc + 32768 + tid * 16;

// half-tile = 128 rows x 128 B = 16 KiB = 2 loads/thread (rows +0 / +64)
#define STAGE_A(nb, kt, h)                                                                  \
    do {                                                                                    \
        async_cp16(srcA0 + (size_t)(kt) * 128 + (h) * 524288,                               \
                   dstA0 + (nb) * 65536 + (h) * 16384);                                     \
        async_cp16(srcA0 + (size_t)(kt) * 128 + (h) * 524288 + 262144,                      \
                   dstA0 + (nb) * 65536 + (h) * 16384 + 8192);                              \
    } while (0)
#define STAGE_B(nb, kt, h)                                                                  \
    do {                                                                                    \
        async_cp16(srcB0 + (size_t)(kt) * 128 + (h) * 524288,                               \
                   dstB0 + (nb) * 65536 + (h) * 16384);                                     \
        async_cp16(srcB0 + (size_t)(kt) * 128 + (h) * 524288 + 262144,                      \
                   dstB0 + (nb) * 65536 + (h) * 16384 + 8192);                              \
    } while (0)

    // ---- read-side swizzled column offsets (per lane, constant all tiles) ----
    int rsw = (l15 & 7) << 4;                 // row&7 == l15&7 for every fragment row
    int colh0 = (q * 16) ^ rsw;               // k-half 0
    int colh1 = colh0 ^ 64;                   // k-half 1 (bit 6 flips cleanly under XOR)
    int arA = (wmw + l15) * 128;
    int arB = (wnw + l15) * 128;

    f32x4 acc[8][4];
#pragma unroll
    for (int a = 0; a < 8; ++a)
#pragma unroll
        for (int b = 0; b < 4; ++b) acc[a][b] = (f32x4){0.f, 0.f, 0.f, 0.f};

    // ---- prologue: tile0 {A,B} -> buf0 (8 loads); t1.B -> buf1 (4 loads) ----
    STAGE_A(0, 0, 0);
    STAGE_A(0, 0, 1);
    STAGE_B(0, 0, 0);
    STAGE_B(0, 0, 1);
    STAGE_B(1, 1, 0);
    STAGE_B(1, 1, 1);
    asm volatile("s_waitcnt vmcnt(4)" ::: "memory");   // tile0 landed; t1.B in flight
    __builtin_amdgcn_s_barrier();
    asm volatile("" ::: "memory");

    int cur = 0;
    for (int t = 0; t < NTK; ++t, cur ^= 1) {
        const int nb = cur ^ 1;
        const char* pa = ldsc + (cur << 16);
        const char* pA0 = pa + arA;
        const char* pB0 = pa + 32768 + arB;

        // ---- top: stage (t+1).A into other buffer (no hazard: nb not read now) ----
        if (t + 1 < NTK) {
            STAGE_A(nb, t + 1, 0);
            STAGE_A(nb, t + 1, 1);
        }

        short8 af[4][2], bf0[2][2], bf1[2][2];

        // ---- first half: read A[m0] + all B, MFMA 2 quads (no barrier inside) ----
#pragma unroll
        for (int tm = 0; tm < 4; ++tm) {
            af[tm][0] = *(const short8*)(pA0 + tm * 2048 + colh0);
            af[tm][1] = *(const short8*)(pA0 + tm * 2048 + colh1);
        }
#pragma unroll
        for (int tn = 0; tn < 2; ++tn) {
            bf0[tn][0] = *(const short8*)(pB0 + tn * 2048 + colh0);
            bf0[tn][1] = *(const short8*)(pB0 + tn * 2048 + colh1);
            bf1[tn][0] = *(const short8*)(pB0 + 4096 + tn * 2048 + colh0);
            bf1[tn][1] = *(const short8*)(pB0 + 4096 + tn * 2048 + colh1);
        }
        mfma_quad<0, 0>(acc, af, bf0);
        mfma_quad<0, 2>(acc, af, bf1);

        // ---- hazard #1: B reads complete -> overwrite cur B with (t+2).B ----
        if (t + 2 < NTK) {
            asm volatile("s_waitcnt lgkmcnt(0)" ::: "memory");
            __builtin_amdgcn_s_barrier();
            asm volatile("" ::: "memory");
            STAGE_B(cur, t + 2, 0);
            STAGE_B(cur, t + 2, 1);
        }

        // ---- second half: read A[m1], MFMA 2 quads (no barrier inside) ----
#pragma unroll
        for (int tm = 0; tm < 4; ++tm) {
            af[tm][0] = *(const short8*)(pA0 + 8192 + tm * 2048 + colh0);
            af[tm][1] = *(const short8*)(pA0 + 8192 + tm * 2048 + colh1);
        }
        mfma_quad<4, 2>(acc, af, bf1);
        mfma_quad<4, 0>(acc, af, bf0);

        // ---- hazard #2 (boundary): all reads done; (t+1) landed; B(t+2) in flight ----
        if (t + 2 < NTK) {
            asm volatile("s_waitcnt vmcnt(4) lgkmcnt(0)" ::: "memory");
            __builtin_amdgcn_s_barrier();
            asm volatile("" ::: "memory");
        } else if (t + 1 < NTK) {
            asm volatile("s_waitcnt vmcnt(0) lgkmcnt(0)" ::: "memory");
            __builtin_amdgcn_s_barrier();
            asm volatile("" ::: "memory");
        }
        // t == NTK-1: fall through to epilogue (registers only)
    }
#undef STAGE_A
#undef STAGE_B

    // ---- epilogue: Out[m][j] bf16,  alpha*acc (- Csub) ----
#pragma unroll
    for (int a = 0; a < 8; ++a) {
        int mbase = m0g + wmw + (a >> 2) * 64 + (a & 3) * 16 + q * 4;
#pragma unroll
        for (int b = 0; b < 4; ++b) {
            int jj = j0g + wnw + (b >> 1) * 32 + (b & 1) * 16 + l15;
#pragma unroll
            for (int r = 0; r < 4; ++r) {
                size_t oidx = (size_t)(mbase + r) * JJ + jj;
                float v = alpha * acc[a][b][r];
                if (Csub) v -= bf2f(Csub[oidx]);
                Out[oidx] = f2bf(v);
            }
        }
    }
}

// ---------------- K5/K6: per-node [192 x 192] @ [192 x 64] MFMA GEMM ----------------
__global__ __launch_bounds__(256) void k_node(const unsigned short* __restrict__ S0,
                                              const unsigned short* __restrict__ S1,
                                              const unsigned short* __restrict__ S2,
                                              const float* __restrict__ E,
                                              const float* __restrict__ Wp,
                                              const float* __restrict__ bias_pool,
                                              const float* __restrict__ mlp_w,
                                              const float* __restrict__ mlp_b,
                                              float* __restrict__ out,
                                              int branch) {
    int n = blockIdx.x, tid = threadIdx.x, lane = tid & 63, wv = tid >> 6;
    __shared__ __align__(16) unsigned short lW[64 * 200];   // W^T: [o][kappa] pad->200
    __shared__ __align__(16) unsigned short lS[192 * 72];   // one source: [m][i] pad->72
    __shared__ float lBias[64];
    int q = lane >> 4, l15 = lane & 15;

    if (branch == 0) {
        float en[ED];
#pragma unroll
        for (int d = 0; d < ED; ++d) en[d] = E[n * ED + d];
        for (int idx = tid; idx < KC * OO; idx += 256) {
            int o = idx & 63, kap = idx >> 6;                  // kap = k*64+i
            float s = 0.f;
#pragma unroll
            for (int d = 0; d < ED; ++d) s += en[d] * Wp[((size_t)d * KC + kap) * OO + o];
            lW[o * 200 + kap] = f2bf(s);
        }
        if (tid < 64) {
            float s = 0.f;
#pragma unroll
            for (int d = 0; d < ED; ++d) s += en[d] * bias_pool[d * OO + tid];
            lBias[tid] = s;
        }
    } else {
        for (int idx = tid; idx < KC * OO; idx += 256) {
            int o = idx & 63, kap = idx >> 6;
            lW[o * 200 + kap] = f2bf(mlp_w[kap * OO + o]);
        }
        if (tid < 64) lBias[tid] = mlp_b[tid];
    }

    f32x4 zero = {0.f, 0.f, 0.f, 0.f};
    f32x4 acc[3][4];
#pragma unroll
    for (int a = 0; a < 3; ++a)
#pragma unroll
        for (int b = 0; b < 4; ++b) acc[a][b] = zero;

    const unsigned short* Ss[3] = { S0 + (size_t)n * JJ, S1 + (size_t)n * JJ, S2 + (size_t)n * JJ };

    for (int s = 0; s < 3; ++s) {
        __syncthreads();
        // stage source row: 12288 bf16 -> lS[m][i] (pad 72)
#pragma unroll
        for (int v = 0; v < 6; ++v) {
            int e8 = (v * 256 + tid) * 8;
            int m = e8 >> 6, i = e8 & 63;
            *(short8*)&lS[m * 72 + i] = *(const short8*)&Ss[s][e8];
        }
        __syncthreads();
#pragma unroll
        for (int h = 0; h < 2; ++h) {
            short8 af[3], bfr[4];
#pragma unroll
            for (int tm = 0; tm < 3; ++tm)
                af[tm] = *(const short8*)&lS[(wv * 48 + tm * 16 + l15) * 72 + h * 32 + q * 8];
#pragma unroll
            for (int tn = 0; tn < 4; ++tn)
                bfr[tn] = *(const short8*)&lW[(tn * 16 + l15) * 200 + s * 64 + h * 32 + q * 8];
#pragma unroll
            for (int tm = 0; tm < 3; ++tm)
#pragma unroll
                for (int tn = 0; tn < 4; ++tn)
                    acc[tm][tn] = __builtin_amdgcn_mfma_f32_16x16x32_bf16(af[tm], bfr[tn], acc[tm][tn], 0, 0, 0);
        }
    }
    // epilogue: out[b][o][n][t] fp32, m = b*T+t
#pragma unroll
    for (int tm = 0; tm < 3; ++tm) {
#pragma unroll
        for (int tn = 0; tn < 4; ++tn) {
            int o = tn * 16 + l15;
#pragma unroll
            for (int r = 0; r < 4; ++r) {
                int m = wv * 48 + tm * 16 + q * 4 + r;
                int b = m / TT, t = m - b * TT;
                out[(((size_t)b * OO + o) * NN + n) * TT + t] = acc[tm][tn][r] + lBias[o];
            }
        }
    }
}

// ---------------- launch ----------------
extern "C" void kernel_launch(void* const* d_in, const int* in_sizes, int n_in,
                              void* d_out, int out_size, void* d_ws, size_t ws_size,
                              hipStream_t stream) {
    const float* x         = (const float*)d_in[0];
    const float* node_emb  = (const float*)d_in[1];
    const float* support   = (const float*)d_in[2];
    const float* wpool     = (const float*)d_in[3];
    const float* bpool     = (const float*)d_in[4];
    const float* mlp_w     = (const float*)d_in[5];
    const float* mlp_b     = (const float*)d_in[6];
    float* out             = (float*)d_out;

    // workspace map (256 MB exactly):
    unsigned short* Abf = (unsigned short*)d_ws;                 // 8 MB
    unsigned short* Atb = Abf + (size_t)NN * NN;                 // 8 MB
    unsigned short* b1  = Atb + (size_t)NN * NN;                 // X2t, later Y2
    unsigned short* b2  = b1 + (size_t)NJ;                       // X2
    unsigned short* b3  = b2 + (size_t)NJ;                       // Y1t, later Z1t
    unsigned short* b4  = b3 + (size_t)NJ;                       // Y1, later Z2
    unsigned short* b5  = b4 + (size_t)NJ;                       // Z1
    // liveness plan:
    //   G13 (z=2): Y1->b4, Z1->b5        (B = X2t = b1)
    //   T1 : b4 -> b3 (Y1t)
    //   G2 : Y2 = 2*A*Y1t - X2 -> b1     (X2t dead)
    //   knode0(X2=b2, Y1=b4, Y2=b1)
    //   T2 : b5 -> b3 (Z1t)
    //   G4 : Z2 = At*Z1t -> b4           (Y1 dead)
    //   knode1(X2=b2, Z1=b5, Z2=b4)

    static int attr_done = 0;
    if (!attr_done) {
        hipFuncSetAttribute(reinterpret_cast<const void*>(k_gemm8),
                            hipFuncAttributeMaxDynamicSharedMemorySize, 131072);
        attr_done = 1;
    }

    dim3 gg13(48, 8, 2);             // merged Y1/Z1 dispatch: 768 blocks = 3 rounds
    dim3 gg1(48, 8, 1);              // single GEMM
    dim3 gt(192, 32);                // transpose grid (64x64 tiles)

    // prep
    k_softmax_A<<<NN, 256, 0, stream>>>(node_emb, Abf);
    k_trans_bf<<<dim3(64, 64), dim3(32, 8), 0, stream>>>(support, Atb);
    k_make_X2<<<NJ / 256, 256, 0, stream>>>(x, b2);              // X2 [n][j]
    k_trans16<<<gt, 256, 0, stream>>>(b2, b1);                   // X2t [j][n]

    // merged: Y1 = A*X2 (z=0), Z1 = At*X2 (z=1)
    k_gemm8<<<gg13, 512, 131072, stream>>>(Abf, Atb, b1, b4, b5, nullptr, 1.0f);

    // adaptive branch tail
    k_trans16<<<gt, 256, 0, stream>>>(b4, b3);                          // Y1t
    k_gemm8<<<gg1, 512, 131072, stream>>>(Abf, Abf, b3, b1, b1, b2, 2.0f);  // Y2 -> b1
    k_node<<<NN, 256, 0, stream>>>(b2, b4, b1, node_emb, wpool, bpool, nullptr, nullptr,
                                   out, 0);

    // diffusion branch tail
    k_trans16<<<gt, 256, 0, stream>>>(b5, b3);                          // Z1t
    k_gemm8<<<gg1, 512, 131072, stream>>>(Atb, Atb, b3, b4, b4, nullptr, 1.0f);  // Z2 -> b4
    k_node<<<NN, 256, 0, stream>>>(b2, b5, b4, nullptr, nullptr, nullptr, mlp_w, mlp_b,
                                   out + (size_t)NJ, 1);
}